// Round 2
// baseline (215.529 us; speedup 1.0000x reference)
//
#include <hip/hip_runtime.h>

// LSTM (B=8192, T=512, H=5) + MLP 5->32->32->5, fp32.
// Round 11: producer/consumer wave split + DPP broadcast restored.
//  - R10 post-mortem: freeing the allocator cut busy 330->286 cyc/step
//    (AGPR churn gone, keep amdgpu_waves_per_eu) but ds_swizzle put DS
//    latency on the h->h chain: stalls 168->241. DPP broadcast restored
//    (R9-proven sequence, ~8 cyc chain).
//  - Structural: 2 waves/block. Wave1 = producer: stages x (proven
//    float4->xbuf scheme, now producer-private) and computes the
//    x-projection zx[G]=sc*(b+Wih*x_t) for 16-step windows into
//    double-buffered zbuf (no recurrence dependence, pure throughput).
//    Wave0 = consumer: ds_read_b128 zx + 20 h-FMA + activations + DPP.
//    2048 waves on 1024 SIMDs = 2/SIMD: producer issue fills consumer
//    chain stalls. 32 barriers (1 per window), parity w&1, safe lockstep.
//  - FMA order preserved (bias -> x0..x4 -> h0..h4): bit-identical math.
//  - LDS 33KB -> still 4 blocks/CU.

#define LOG2E 1.44269504088896f

__device__ __forceinline__ float hexp2(float x) { return __builtin_amdgcn_exp2f(x); }
__device__ __forceinline__ float hrcp(float x)  { return __builtin_amdgcn_rcpf(x); }

// plain DPP move (all lanes written)
template<int CTRL>
__device__ __forceinline__ float dpp_mov(float x) {
  int r = __builtin_amdgcn_update_dpp(0, __builtin_bit_cast(int, x),
                                      CTRL, 0xF, 0xF, true);
  return __builtin_bit_cast(float, r);
}
// masked DPP merge: enabled banks get shifted src, others keep `old`
template<int CTRL, int BANKMASK>
__device__ __forceinline__ float dpp_merge(float old, float src) {
  int r = __builtin_amdgcn_update_dpp(__builtin_bit_cast(int, old),
                                      __builtin_bit_cast(int, src),
                                      CTRL, 0xF, BANKMASK, false);
  return __builtin_bit_cast(float, r);
}

constexpr int TT   = 512;
constexpr int HD   = 5;
constexpr int RPB  = 8;     // rows per block (8 lanes each)
constexpr int CHNK = 32;    // steps per x-staging chunk
constexpr int RSTR = 164;   // padded xbuf row stride
constexpr int XOFF = RPB * RSTR;      // 1312
constexpr int NCH  = TT / CHNK;       // 16
constexpr int WST  = 16;              // steps per zbuf window
constexpr int ZSTR = 20;              // floats per (t,grp) cell (5 units x 4 gates)
constexpr int ZROW = RPB * ZSTR;      // 160 floats per step
constexpr int ZWIN = WST * ZROW;      // 2560 floats per window buffer

__global__ __attribute__((amdgpu_flat_work_group_size(128, 128),
                          amdgpu_waves_per_eu(2, 2)))
void lstm_mlp_kernel(
    const float* __restrict__ x,   const float* __restrict__ Wih,
    const float* __restrict__ Whh, const float* __restrict__ bih,
    const float* __restrict__ bhh, const float* __restrict__ W1,
    const float* __restrict__ b1,  const float* __restrict__ W2,
    const float* __restrict__ b2,  const float* __restrict__ W3,
    const float* __restrict__ b3,  float* __restrict__ out, int B)
{
  const int tid  = threadIdx.x;
  const int wid  = tid >> 6;            // 0 = consumer, 1 = producer
  const int lane = tid & 63;
  const int grp  = lane >> 3;           // row within block (0..7)
  const int j    = lane & 7;            // unit owned (valid if j<5)
  const int jj   = (j < 5) ? j : 0;
  const int blockRow = blockIdx.x * RPB;
  const int row  = blockRow + grp;

  __shared__ __align__(16) float xbuf[2 * XOFF];   // producer-private
  __shared__ __align__(16) float zbuf[2 * ZWIN];   // producer -> consumer
  __shared__ float s1[RPB][32];
  __shared__ float s2[RPB][32];

  if (wid == 1) {
    // ========================== producer ==========================
    float wih[4][5], bsum[4];
#pragma unroll
    for (int G = 0; G < 4; ++G) {
      const float sc = (G == 2) ? (2.0f * LOG2E) : (-LOG2E);
#pragma unroll
      for (int k = 0; k < 5; ++k)
        wih[G][k] = Wih[(G * 5 + jj) * 5 + k] * sc;
      bsum[G] = (bih[G * 5 + jj] + bhh[G * 5 + jj]) * sc;
    }

    // staging: 5x16B per lane per 32-step chunk (proven addressing)
    const float4* gp[5];
    int wa[5];
#pragma unroll
    for (int i = 0; i < 5; ++i) {
      int u  = i * 64 + lane;
      int r  = u / 40;
      int o4 = u - r * 40;
      int gr = blockRow + r; if (gr >= B) gr = B - 1;
      gp[i]  = (const float4*)(x + (size_t)gr * (TT * HD)) + o4;
      wa[i]  = r * RSTR + o4 * 4;
    }

    float4 st0, st1, st2, st3, st4;
    st0 = *gp[0]; gp[0] += 40; st1 = *gp[1]; gp[1] += 40;
    st2 = *gp[2]; gp[2] += 40; st3 = *gp[3]; gp[3] += 40;
    st4 = *gp[4]; gp[4] += 40;
    *(float4*)&xbuf[wa[0]] = st0; *(float4*)&xbuf[wa[1]] = st1;
    *(float4*)&xbuf[wa[2]] = st2; *(float4*)&xbuf[wa[3]] = st3;
    *(float4*)&xbuf[wa[4]] = st4;
    st0 = *gp[0]; gp[0] += 40; st1 = *gp[1]; gp[1] += 40;
    st2 = *gp[2]; gp[2] += 40; st3 = *gp[3]; gp[3] += 40;
    st4 = *gp[4]; gp[4] += 40;

    float* zb = zbuf + grp * ZSTR + jj * 4;  // + par*ZWIN + t*ZROW

    auto prodstep = [&](float x0, float x1, float x2, float x3, float x4,
                        float* zp) {
      float a[4];
#pragma unroll
      for (int G = 0; G < 4; ++G) {
        float a0 = bsum[G];
        a0 = fmaf(x0, wih[G][0], a0);
        a0 = fmaf(x1, wih[G][1], a0);
        a0 = fmaf(x2, wih[G][2], a0);
        a0 = fmaf(x3, wih[G][3], a0);
        a0 = fmaf(x4, wih[G][4], a0);
        a[G] = a0;
      }
      if (j < 5) {
        float4 v; v.x = a[0]; v.y = a[1]; v.z = a[2]; v.w = a[3];
        *(float4*)zp = v;
      }
    };
    auto prod4 = [&](float4 A, float4 Bv, float4 C, float4 D, float4 E,
                     float* zp) {
      prodstep(A.x, A.y, A.z, A.w, Bv.x, zp);
      prodstep(Bv.y, Bv.z, Bv.w, C.x, C.y, zp + 1 * ZROW);
      prodstep(C.z, C.w, D.x, D.y, D.z, zp + 2 * ZROW);
      prodstep(D.w, E.x, E.y, E.z, E.w, zp + 3 * ZROW);
    };
    auto rdg = [&](int fi, float4& A, float4& Bv, float4& C, float4& D, float4& E) {
      const float4* p = (const float4*)&xbuf[fi];
      A = p[0]; Bv = p[1]; C = p[2]; D = p[3]; E = p[4];
    };

    float4 A0, A1, A2, A3, A4;
    float4 B0, B1, B2, B3, B4;

#pragma unroll 1
    for (int ch = 0; ch < NCH; ++ch) {
      const int bo_cur  = (ch & 1) ? XOFF : 0;
      const int bo_next = XOFF - bo_cur;
      if (ch < NCH - 1) {
        *(float4*)&xbuf[wa[0] + bo_next] = st0;
        *(float4*)&xbuf[wa[1] + bo_next] = st1;
        *(float4*)&xbuf[wa[2] + bo_next] = st2;
        *(float4*)&xbuf[wa[3] + bo_next] = st3;
        *(float4*)&xbuf[wa[4] + bo_next] = st4;
      }
      if (ch < NCH - 2) {
        st0 = *gp[0]; gp[0] += 40; st1 = *gp[1]; gp[1] += 40;
        st2 = *gp[2]; gp[2] += 40; st3 = *gp[3]; gp[3] += 40;
        st4 = *gp[4]; gp[4] += 40;
      }
      const int xb = bo_cur + grp * RSTR;

      // half 0 -> zbuf parity 0 (window w = 2*ch)
      rdg(xb +  0, A0, A1, A2, A3, A4);
      rdg(xb + 20, B0, B1, B2, B3, B4);
      prod4(A0, A1, A2, A3, A4, zb + 0 * ZROW);
      rdg(xb + 40, A0, A1, A2, A3, A4);
      prod4(B0, B1, B2, B3, B4, zb + 4 * ZROW);
      rdg(xb + 60, B0, B1, B2, B3, B4);
      prod4(A0, A1, A2, A3, A4, zb +  8 * ZROW);
      prod4(B0, B1, B2, B3, B4, zb + 12 * ZROW);
      __syncthreads();

      // half 1 -> zbuf parity 1 (window w = 2*ch+1)
      float* z1 = zb + ZWIN;
      rdg(xb +  80, A0, A1, A2, A3, A4);
      rdg(xb + 100, B0, B1, B2, B3, B4);
      prod4(A0, A1, A2, A3, A4, z1 + 0 * ZROW);
      rdg(xb + 120, A0, A1, A2, A3, A4);
      prod4(B0, B1, B2, B3, B4, z1 + 4 * ZROW);
      rdg(xb + 140, B0, B1, B2, B3, B4);
      prod4(A0, A1, A2, A3, A4, z1 +  8 * ZROW);
      prod4(B0, B1, B2, B3, B4, z1 + 12 * ZROW);
      __syncthreads();
    }
    return;  // producer done: 32 barriers executed, no MLP
  }

  // ========================== consumer ==========================
  float whh[4][5];
#pragma unroll
  for (int G = 0; G < 4; ++G) {
    const float sc = (G == 2) ? (2.0f * LOG2E) : (-LOG2E);
#pragma unroll
    for (int k = 0; k < 5; ++k)
      whh[G][k] = Whh[(G * 5 + jj) * 5 + k] * sc;
  }

  const int rowc = (row < B) ? row : (B - 1);
  const float xl0 = x[(size_t)rowc * (TT * HD) + 511 * HD + 0];
  const float xl1 = x[(size_t)rowc * (TT * HD) + 511 * HD + 1];
  const float xl2 = x[(size_t)rowc * (TT * HD) + 511 * HD + 2];
  const float xl3 = x[(size_t)rowc * (TT * HD) + 511 * HD + 3];
  const float xl4 = x[(size_t)rowc * (TT * HD) + 511 * HD + 4];

  float c = 0.0f;
  float hv0 = 0.f, hv1 = 0.f, hv2 = 0.f, hv3 = 0.f, hv4 = 0.f;

  auto stepz = [&](float4 zn) {
    float z[4] = {zn.x, zn.y, zn.z, zn.w};  // sc*(b + Wih*x_t), gate i,f,g,o
#pragma unroll
    for (int G = 0; G < 4; ++G) {
      float a = z[G];
      a = fmaf(hv0, whh[G][0], a);
      a = fmaf(hv1, whh[G][1], a);
      a = fmaf(hv2, whh[G][2], a);
      a = fmaf(hv3, whh[G][3], a);
      a = fmaf(hv4, whh[G][4], a);
      z[G] = a;
    }
    float ig = hrcp(1.0f + hexp2(z[0]));
    float fg = hrcp(1.0f + hexp2(z[1]));
    float gv = fmaf(-2.0f, hrcp(1.0f + hexp2(z[2])), 1.0f);
    float og = hrcp(1.0f + hexp2(z[3]));
    c = fmaf(fg, c, ig * gv);
    float th = fmaf(-2.0f, hrcp(1.0f + hexp2(c * (2.0f * LOG2E))), 1.0f);
    float h  = og * th;
    // R9-proven 8-lane-group broadcast: 4 quad movs + 5 masked merges
    float q0 = dpp_mov<0x00>(h);
    float q1 = dpp_mov<0x55>(h);
    float q2 = dpp_mov<0xAA>(h);
    float q3 = dpp_mov<0xFF>(h);
    hv0 = dpp_merge<0x114, 0xA>(q0, q0);
    hv1 = dpp_merge<0x114, 0xA>(q1, q1);
    hv2 = dpp_merge<0x114, 0xA>(q2, q2);
    hv3 = dpp_merge<0x114, 0xA>(q3, q3);
    hv4 = dpp_merge<0x104, 0x5>(q0, q0);
  };

#pragma unroll 1
  for (int w = 0; w < 2 * NCH; ++w) {
    __syncthreads();   // window w ready in zbuf[w&1]
    const float4* zp = (const float4*)(zbuf + (w & 1) * ZWIN) + (grp * 5 + jj);
    // step t lives at zp[t*40] (ZROW=160 floats = 40 float4)
    float4 ZA0 = zp[0],   ZA1 = zp[40],  ZA2 = zp[80],  ZA3 = zp[120];
    float4 ZB0 = zp[160], ZB1 = zp[200], ZB2 = zp[240], ZB3 = zp[280];
    stepz(ZA0); stepz(ZA1); stepz(ZA2); stepz(ZA3);
    ZA0 = zp[320]; ZA1 = zp[360]; ZA2 = zp[400]; ZA3 = zp[440];
    stepz(ZB0); stepz(ZB1); stepz(ZB2); stepz(ZB3);
    ZB0 = zp[480]; ZB1 = zp[520]; ZB2 = zp[560]; ZB3 = zp[600];
    stepz(ZA0); stepz(ZA1); stepz(ZA2); stepz(ZA3);
    stepz(ZB0); stepz(ZB1); stepz(ZB2); stepz(ZB3);
  }

  // ---- MLP head (consumer wave only; no barriers needed) ----
  const bool act = (j < 5) && (row < B);
  float in5_0 = hv0 + xl0, in5_1 = hv1 + xl1, in5_2 = hv2 + xl2,
        in5_3 = hv3 + xl3, in5_4 = hv4 + xl4;

#pragma unroll
  for (int p = 0; p < 4; ++p) {
    int m = p * 8 + j;
    float acc = b1[m];
    acc = fmaf(W1[m * 5 + 0], in5_0, acc);
    acc = fmaf(W1[m * 5 + 1], in5_1, acc);
    acc = fmaf(W1[m * 5 + 2], in5_2, acc);
    acc = fmaf(W1[m * 5 + 3], in5_3, acc);
    acc = fmaf(W1[m * 5 + 4], in5_4, acc);
    s1[grp][m] = fmaxf(acc, 0.0f);
  }
  float y1[32];
#pragma unroll
  for (int k = 0; k < 32; ++k) y1[k] = s1[grp][k];

  auto dot32 = [&](const float* W, int m, const float* y, float b) {
    float acc = b;
    const float4* w4 = (const float4*)(W + m * 32);
#pragma unroll
    for (int k4 = 0; k4 < 8; ++k4) {
      float4 w = w4[k4];
      acc = fmaf(w.x, y[k4 * 4 + 0], acc);
      acc = fmaf(w.y, y[k4 * 4 + 1], acc);
      acc = fmaf(w.z, y[k4 * 4 + 2], acc);
      acc = fmaf(w.w, y[k4 * 4 + 3], acc);
    }
    return acc;
  };

#pragma unroll
  for (int p = 0; p < 4; ++p) {
    int m = p * 8 + j;
    s2[grp][m] = fmaxf(dot32(W2, m, y1, b2[m]), 0.0f);
  }
  float y2[32];
#pragma unroll
  for (int k = 0; k < 32; ++k) y2[k] = s2[grp][k];

  if (act) out[row * HD + j] = dot32(W3, j, y2, b3[j]);
}

extern "C" void kernel_launch(void* const* d_in, const int* in_sizes, int n_in,
                              void* d_out, int out_size, void* d_ws, size_t ws_size,
                              hipStream_t stream) {
  const float* x   = (const float*)d_in[0];
  const float* Wih = (const float*)d_in[1];
  const float* Whh = (const float*)d_in[2];
  const float* bih = (const float*)d_in[3];
  const float* bhh = (const float*)d_in[4];
  const float* W1  = (const float*)d_in[5];
  const float* b1  = (const float*)d_in[6];
  const float* W2  = (const float*)d_in[7];
  const float* b2  = (const float*)d_in[8];
  const float* W3  = (const float*)d_in[9];
  const float* b3  = (const float*)d_in[10];

  int B = in_sizes[0] / (TT * HD);
  int grid = (B + RPB - 1) / RPB;
  hipLaunchKernelGGL(lstm_mlp_kernel, dim3(grid), dim3(128), 0, stream,
                     x, Wih, Whh, bih, bhh, W1, b1, W2, b2, W3, b3,
                     (float*)d_out, B);
}

// Round 3
// 204.507 us; speedup vs baseline: 1.0539x; 1.0539x over previous
//
#include <hip/hip_runtime.h>

// LSTM (B=8192, T=512, H=5) + MLP 5->32->32->5, fp32.
// Round 12: single wave + explicit 2-stage software pipeline.
//  - R11 post-mortem: producer/consumer is net-zero — producer issue
//    steals the shared SIMD port exactly as fast as it fills consumer
//    bubbles, plus 32-barrier lockstep overhead. Latency-bound truth:
//    T = 512 x wall(step) of ONE wave. Minimize that.
//  - Calibration (R9/R10 counters): trans ops ~16 cyc issue each; issue
//    ~290/step, wall ~500 -> ~215 cyc of trans-latency bubbles on the
//    c->tanh->h chain. Only independent filler: next step's x-part
//    (20 FMA). This round pipelines it explicitly: x-part(t+1) computed
//    inside step t's activation phase (half after the gate exps, half
//    after the c-update, in the two biggest latency shadows).
//  - Per-gate FP order preserved (bias -> x0..x4 -> h0..h4): results
//    bit-identical to R9/R10.
//  - Keeps: freed allocator (R10), DPP broadcast (R9), LDS x-staging
//    with RSTR=164 conflict-free layout (R8), pre-folded scales (R7).

#define LOG2E 1.44269504088896f

__device__ __forceinline__ float hexp2(float x) { return __builtin_amdgcn_exp2f(x); }
__device__ __forceinline__ float hrcp(float x)  { return __builtin_amdgcn_rcpf(x); }

template<int CTRL>
__device__ __forceinline__ float dpp_mov(float x) {
  int r = __builtin_amdgcn_update_dpp(0, __builtin_bit_cast(int, x),
                                      CTRL, 0xF, 0xF, true);
  return __builtin_bit_cast(float, r);
}
template<int CTRL, int BANKMASK>
__device__ __forceinline__ float dpp_merge(float old, float src) {
  int r = __builtin_amdgcn_update_dpp(__builtin_bit_cast(int, old),
                                      __builtin_bit_cast(int, src),
                                      CTRL, 0xF, BANKMASK, false);
  return __builtin_bit_cast(float, r);
}

constexpr int TT   = 512;
constexpr int HD   = 5;
constexpr int RPB  = 8;     // rows per wave (8 lanes each)
constexpr int CHNK = 32;    // steps per LDS chunk
constexpr int RSTR = 164;   // padded LDS row stride
constexpr int XOFF = RPB * RSTR;
constexpr int NCH  = TT / CHNK;

__global__ __attribute__((amdgpu_flat_work_group_size(64, 64),
                          amdgpu_waves_per_eu(1, 1)))
void lstm_mlp_kernel(
    const float* __restrict__ x,   const float* __restrict__ Wih,
    const float* __restrict__ Whh, const float* __restrict__ bih,
    const float* __restrict__ bhh, const float* __restrict__ W1,
    const float* __restrict__ b1,  const float* __restrict__ W2,
    const float* __restrict__ b2,  const float* __restrict__ W3,
    const float* __restrict__ b3,  float* __restrict__ out, int B)
{
  const int lane = threadIdx.x;
  const int grp  = lane >> 3;           // row within block (0..7)
  const int j    = lane & 7;            // unit owned (valid if j<5)
  const int jj   = (j < 5) ? j : 0;
  const int blockRow = blockIdx.x * RPB;
  const int row  = blockRow + grp;
  const bool act = (j < 5) && (row < B);

  __shared__ __align__(16) float xbuf[2 * XOFF];
  __shared__ float s1[RPB][32];
  __shared__ float s2[RPB][32];

  // ---- per-lane weights (rows {j,5+j,10+j,15+j}), activation pre-scaled --
  float wih[4][5], whh[4][5], bsum[4];
#pragma unroll
  for (int G = 0; G < 4; ++G) {
    const float sc = (G == 2) ? (2.0f * LOG2E) : (-LOG2E);
#pragma unroll
    for (int k = 0; k < 5; ++k) {
      wih[G][k] = Wih[(G * 5 + jj) * 5 + k] * sc;
      whh[G][k] = Whh[(G * 5 + jj) * 5 + k] * sc;
    }
    bsum[G] = (bih[G * 5 + jj] + bhh[G * 5 + jj]) * sc;
  }

  const int rowc = (row < B) ? row : (B - 1);
  const float xl0 = x[(size_t)rowc * (TT * HD) + 511 * HD + 0];
  const float xl1 = x[(size_t)rowc * (TT * HD) + 511 * HD + 1];
  const float xl2 = x[(size_t)rowc * (TT * HD) + 511 * HD + 2];
  const float xl3 = x[(size_t)rowc * (TT * HD) + 511 * HD + 3];
  const float xl4 = x[(size_t)rowc * (TT * HD) + 511 * HD + 4];

  // ---- staging: 5x16B per lane per 32-step chunk (R8-proven) ----
  const float4* gp[5];
  int wa[5];
#pragma unroll
  for (int i = 0; i < 5; ++i) {
    int u  = i * 64 + lane;
    int r  = u / 40;
    int o4 = u - r * 40;
    int gr = blockRow + r; if (gr >= B) gr = B - 1;
    gp[i]  = (const float4*)(x + (size_t)gr * (TT * HD)) + o4;
    wa[i]  = r * RSTR + o4 * 4;
  }

  float4 st0, st1, st2, st3, st4;
  st0 = *gp[0]; gp[0] += 40; st1 = *gp[1]; gp[1] += 40;
  st2 = *gp[2]; gp[2] += 40; st3 = *gp[3]; gp[3] += 40;
  st4 = *gp[4]; gp[4] += 40;
  *(float4*)&xbuf[wa[0]] = st0; *(float4*)&xbuf[wa[1]] = st1;
  *(float4*)&xbuf[wa[2]] = st2; *(float4*)&xbuf[wa[3]] = st3;
  *(float4*)&xbuf[wa[4]] = st4;
  st0 = *gp[0]; gp[0] += 40; st1 = *gp[1]; gp[1] += 40;
  st2 = *gp[2]; gp[2] += 40; st3 = *gp[3]; gp[3] += 40;
  st4 = *gp[4]; gp[4] += 40;

  // ---- recurrence state ----
  float c = 0.0f;
  float hv0 = 0.f, hv1 = 0.f, hv2 = 0.f, hv3 = 0.f, hv4 = 0.f;
  float zx0, zx1, zx2, zx3;   // x-part (+bias) of CURRENT step, pre-scaled

  // prologue: zx for step 0 from the just-written chunk-0 buffer
  {
    const float* xp = &xbuf[grp * RSTR];
    float p0 = xp[0], p1 = xp[1], p2 = xp[2], p3 = xp[3], p4 = xp[4];
    zx0 = bsum[0];
    zx0 = fmaf(p0, wih[0][0], zx0); zx0 = fmaf(p1, wih[0][1], zx0);
    zx0 = fmaf(p2, wih[0][2], zx0); zx0 = fmaf(p3, wih[0][3], zx0);
    zx0 = fmaf(p4, wih[0][4], zx0);
    zx1 = bsum[1];
    zx1 = fmaf(p0, wih[1][0], zx1); zx1 = fmaf(p1, wih[1][1], zx1);
    zx1 = fmaf(p2, wih[1][2], zx1); zx1 = fmaf(p3, wih[1][3], zx1);
    zx1 = fmaf(p4, wih[1][4], zx1);
    zx2 = bsum[2];
    zx2 = fmaf(p0, wih[2][0], zx2); zx2 = fmaf(p1, wih[2][1], zx2);
    zx2 = fmaf(p2, wih[2][2], zx2); zx2 = fmaf(p3, wih[2][3], zx2);
    zx2 = fmaf(p4, wih[2][4], zx2);
    zx3 = bsum[3];
    zx3 = fmaf(p0, wih[3][0], zx3); zx3 = fmaf(p1, wih[3][1], zx3);
    zx3 = fmaf(p2, wih[3][2], zx3); zx3 = fmaf(p3, wih[3][3], zx3);
    zx3 = fmaf(p4, wih[3][4], zx3);
  }

  // pipelined step: consumes zx (current step), computes next zx from
  // n0..n4 = NEXT step's x values, interleaved into the latency shadows.
  auto stepP = [&](float n0, float n1, float n2, float n3, float n4) {
    // h-part (chain head): z = zx + Whh*h, order h0..h4 per gate
    float z0 = zx0, z1 = zx1, z2 = zx2, z3 = zx3;
    z0 = fmaf(hv0, whh[0][0], z0); z0 = fmaf(hv1, whh[0][1], z0);
    z0 = fmaf(hv2, whh[0][2], z0); z0 = fmaf(hv3, whh[0][3], z0);
    z0 = fmaf(hv4, whh[0][4], z0);
    z1 = fmaf(hv0, whh[1][0], z1); z1 = fmaf(hv1, whh[1][1], z1);
    z1 = fmaf(hv2, whh[1][2], z1); z1 = fmaf(hv3, whh[1][3], z1);
    z1 = fmaf(hv4, whh[1][4], z1);
    z2 = fmaf(hv0, whh[2][0], z2); z2 = fmaf(hv1, whh[2][1], z2);
    z2 = fmaf(hv2, whh[2][2], z2); z2 = fmaf(hv3, whh[2][3], z2);
    z2 = fmaf(hv4, whh[2][4], z2);
    z3 = fmaf(hv0, whh[3][0], z3); z3 = fmaf(hv1, whh[3][1], z3);
    z3 = fmaf(hv2, whh[3][2], z3); z3 = fmaf(hv3, whh[3][3], z3);
    z3 = fmaf(hv4, whh[3][4], z3);
    // gate exps issue first...
    float e0 = hexp2(z0), e1 = hexp2(z1), e2 = hexp2(z2), e3 = hexp2(z3);
    // ...latency shadow #1: next-step x-part, gates 0,1 (independent)
    float n_0 = bsum[0];
    n_0 = fmaf(n0, wih[0][0], n_0); n_0 = fmaf(n1, wih[0][1], n_0);
    n_0 = fmaf(n2, wih[0][2], n_0); n_0 = fmaf(n3, wih[0][3], n_0);
    n_0 = fmaf(n4, wih[0][4], n_0);
    float n_1 = bsum[1];
    n_1 = fmaf(n0, wih[1][0], n_1); n_1 = fmaf(n1, wih[1][1], n_1);
    n_1 = fmaf(n2, wih[1][2], n_1); n_1 = fmaf(n3, wih[1][3], n_1);
    n_1 = fmaf(n4, wih[1][4], n_1);
    // finish gate activations (c-chain priority order)
    float fg = hrcp(1.0f + e1);
    float ig = hrcp(1.0f + e0);
    float gr = hrcp(1.0f + e2);
    float og = hrcp(1.0f + e3);
    float gv = fmaf(-2.0f, gr, 1.0f);
    c = fmaf(fg, c, ig * gv);
    float cm = c * (2.0f * LOG2E);
    float ec = hexp2(cm);
    // ...latency shadow #2: next-step x-part, gates 2,3
    float n_2 = bsum[2];
    n_2 = fmaf(n0, wih[2][0], n_2); n_2 = fmaf(n1, wih[2][1], n_2);
    n_2 = fmaf(n2, wih[2][2], n_2); n_2 = fmaf(n3, wih[2][3], n_2);
    n_2 = fmaf(n4, wih[2][4], n_2);
    float n_3 = bsum[3];
    n_3 = fmaf(n0, wih[3][0], n_3); n_3 = fmaf(n1, wih[3][1], n_3);
    n_3 = fmaf(n2, wih[3][2], n_3); n_3 = fmaf(n3, wih[3][3], n_3);
    n_3 = fmaf(n4, wih[3][4], n_3);
    // tail
    float th = fmaf(-2.0f, hrcp(1.0f + ec), 1.0f);
    float h  = og * th;
    // R9-proven 8-lane-group broadcast
    float q0 = dpp_mov<0x00>(h);
    float q1 = dpp_mov<0x55>(h);
    float q2 = dpp_mov<0xAA>(h);
    float q3 = dpp_mov<0xFF>(h);
    hv0 = dpp_merge<0x114, 0xA>(q0, q0);
    hv1 = dpp_merge<0x114, 0xA>(q1, q1);
    hv2 = dpp_merge<0x114, 0xA>(q2, q2);
    hv3 = dpp_merge<0x114, 0xA>(q3, q3);
    hv4 = dpp_merge<0x104, 0x5>(q0, q0);
    zx0 = n_0; zx1 = n_1; zx2 = n_2; zx3 = n_3;
  };

  float4 A0, A1, A2, A3, A4;
  float4 B0, B1, B2, B3, B4;

  auto rdg = [&](int fi, float4& A, float4& Bv, float4& C, float4& D, float4& E) {
    const float4* p = (const float4*)&xbuf[fi];
    A = p[0]; Bv = p[1]; C = p[2]; D = p[3]; E = p[4];
  };

  // SUBA: steps s..s+3 (zx ready); next-x = window elems 5..24 (A tail + B head)
  auto SUBA = [&]() {
    stepP(A1.y, A1.z, A1.w, A2.x, A2.y);
    stepP(A2.z, A2.w, A3.x, A3.y, A3.z);
    stepP(A3.w, A4.x, A4.y, A4.z, A4.w);
    stepP(B0.x, B0.y, B0.z, B0.w, B1.x);
  };
  // SUBB: steps s+4..s+7; next-x = B tail + (refreshed) A head
  auto SUBB = [&]() {
    stepP(B1.y, B1.z, B1.w, B2.x, B2.y);
    stepP(B2.z, B2.w, B3.x, B3.y, B3.z);
    stepP(B3.w, B4.x, B4.y, B4.z, B4.w);
    stepP(A0.x, A0.y, A0.z, A0.w, A1.x);
  };

#pragma unroll 1
  for (int ch = 0; ch < NCH; ++ch) {
    const int bo_cur  = (ch & 1) ? XOFF : 0;
    const int bo_next = XOFF - bo_cur;
    if (ch < NCH - 1) {
      *(float4*)&xbuf[wa[0] + bo_next] = st0;
      *(float4*)&xbuf[wa[1] + bo_next] = st1;
      *(float4*)&xbuf[wa[2] + bo_next] = st2;
      *(float4*)&xbuf[wa[3] + bo_next] = st3;
      *(float4*)&xbuf[wa[4] + bo_next] = st4;
    }
    if (ch < NCH - 2) {
      st0 = *gp[0]; gp[0] += 40; st1 = *gp[1]; gp[1] += 40;
      st2 = *gp[2]; gp[2] += 40; st3 = *gp[3]; gp[3] += 40;
      st4 = *gp[4]; gp[4] += 40;
    }
    const int xb = bo_cur + grp * RSTR;
    rdg(xb +   0, A0, A1, A2, A3, A4);
    rdg(xb +  20, B0, B1, B2, B3, B4);
    SUBA(); rdg(xb +  40, A0, A1, A2, A3, A4);
    SUBB(); rdg(xb +  60, B0, B1, B2, B3, B4);
    SUBA(); rdg(xb +  80, A0, A1, A2, A3, A4);
    SUBB(); rdg(xb + 100, B0, B1, B2, B3, B4);
    SUBA(); rdg(xb + 120, A0, A1, A2, A3, A4);
    SUBB(); rdg(xb + 140, B0, B1, B2, B3, B4);
    SUBA();
    // cross-chunk: next chunk's first group (already staged above; for
    // the last chunk this yields a dead zx that is never consumed)
    rdg(bo_next + grp * RSTR, A0, A1, A2, A3, A4);
    SUBB();
  }

  // ---- MLP head (single wave; no barriers needed) ----
  float in5_0 = hv0 + xl0, in5_1 = hv1 + xl1, in5_2 = hv2 + xl2,
        in5_3 = hv3 + xl3, in5_4 = hv4 + xl4;

#pragma unroll
  for (int p = 0; p < 4; ++p) {
    int m = p * 8 + j;
    float acc = b1[m];
    acc = fmaf(W1[m * 5 + 0], in5_0, acc);
    acc = fmaf(W1[m * 5 + 1], in5_1, acc);
    acc = fmaf(W1[m * 5 + 2], in5_2, acc);
    acc = fmaf(W1[m * 5 + 3], in5_3, acc);
    acc = fmaf(W1[m * 5 + 4], in5_4, acc);
    s1[grp][m] = fmaxf(acc, 0.0f);
  }
  float y1[32];
#pragma unroll
  for (int k = 0; k < 32; ++k) y1[k] = s1[grp][k];

  auto dot32 = [&](const float* W, int m, const float* y, float b) {
    float acc = b;
    const float4* w4 = (const float4*)(W + m * 32);
#pragma unroll
    for (int k4 = 0; k4 < 8; ++k4) {
      float4 w = w4[k4];
      acc = fmaf(w.x, y[k4 * 4 + 0], acc);
      acc = fmaf(w.y, y[k4 * 4 + 1], acc);
      acc = fmaf(w.z, y[k4 * 4 + 2], acc);
      acc = fmaf(w.w, y[k4 * 4 + 3], acc);
    }
    return acc;
  };

#pragma unroll
  for (int p = 0; p < 4; ++p) {
    int m = p * 8 + j;
    s2[grp][m] = fmaxf(dot32(W2, m, y1, b2[m]), 0.0f);
  }
  float y2[32];
#pragma unroll
  for (int k = 0; k < 32; ++k) y2[k] = s2[grp][k];

  if (act) out[row * HD + j] = dot32(W3, j, y2, b3[j]);
}

extern "C" void kernel_launch(void* const* d_in, const int* in_sizes, int n_in,
                              void* d_out, int out_size, void* d_ws, size_t ws_size,
                              hipStream_t stream) {
  const float* x   = (const float*)d_in[0];
  const float* Wih = (const float*)d_in[1];
  const float* Whh = (const float*)d_in[2];
  const float* bih = (const float*)d_in[3];
  const float* bhh = (const float*)d_in[4];
  const float* W1  = (const float*)d_in[5];
  const float* b1  = (const float*)d_in[6];
  const float* W2  = (const float*)d_in[7];
  const float* b2  = (const float*)d_in[8];
  const float* W3  = (const float*)d_in[9];
  const float* b3  = (const float*)d_in[10];

  int B = in_sizes[0] / (TT * HD);
  int grid = (B + RPB - 1) / RPB;
  hipLaunchKernelGGL(lstm_mlp_kernel, dim3(grid), dim3(64), 0, stream,
                     x, Wih, Whh, bih, bhh, W1, b1, W2, b2, W3, b3,
                     (float*)d_out, B);
}